// Round 6
// baseline (47378.012 us; speedup 1.0000x reference)
//
#include <hip/hip_runtime.h>
#include <hip/hip_bf16.h>
#include <hip/hip_cooperative_groups.h>
#include <math.h>

namespace cg = cooperative_groups;

#define NN 65536
#define MATD 131072L   // doubles per complex matrix (re plane + im plane)
#define MAT0 32768L    // header size in doubles

// ws header offsets (doubles)
#define SC_DT 0
#define SC_NUINV 3
#define SC_EXPM_S 4
#define SC_EXPM_SCALE 5
#define SC_NORMS2 6
// 8,9: n1,ninf of M ; 12,13: n1,ninf of S ; 14: F^2 of S
#define W_UNIT_RE 64
#define W_UNIT_IM 320
#define W_C_RE 576
#define W_C_IM 832
#define W_LD_RE 1088
#define W_LD_IM 1344
#define W_SU 1600
#define W_SLOT 1856
#define W_SLOTU 2112        // 256 entries -> ends 2368
#define W_W 2432            // 256*33*2 doubles -> ends 19328
// cooperative-chain scratch (zeroed by k_init)
#define RS_A 22528
#define RS_B 22784
#define CS_M 23040
#define RS_M 23296
#define CS_MI 23552
#define CS_I 23808
#define RS_I 24064
#define NPOOL 256           // virtual pool capacity (every unit can be pooled)

// matrix slots
#define S_EW 0
#define S_NUW 1
#define S_LAT 2
#define S_T2 3
#define S_T3 4
#define S_T4 5
#define S_E1 6
#define S_E2 7
#define S_M 8
#define S_M2 9
#define S_Y 10
#define S_Y2 11
#define S_IY 12
#define S_X 13
#define S_X2 14
#define S_T 15
#define S_W 16
#define S_V 17
#define S_G 18
#define S_G2 19
#define PBASE 20            // S^k at PBASE+k-1, k=1..32 -> 20..51
#define POOL0 52            // physical pool: A at 52..52+K-1, B at 52+K..52+2K-1

#define PI_D 3.14159265358979323846

__device__ inline double ldin(const void* p, int i, int dt){
    if (dt == 0) return (double)__bfloat162float(((const __hip_bfloat16*)p)[i]);
    if (dt == 1) return (double)((const float*)p)[i];
    return ((const double*)p)[i];
}

// ---------------- init: zero header ----------------
__global__ __launch_bounds__(256) void k_init(double* ws){
    ws[blockIdx.x * 256 + threadIdx.x] = 0.0;   // grid 128 -> 32768
}

// ---------------- input dtype detection ----------------
__global__ __launch_bounds__(64) void k_detect(const void* x, double* ws){
    __shared__ int ok[3];
    int t = threadIdx.x;
    if (t < 3) ok[t] = 1;
    __syncthreads();
    const __hip_bfloat16* pb = (const __hip_bfloat16*)x;
    for (int k = t; k < 256; k += 64){
        float v = __bfloat162float(pb[k]);
        if (!(v > 0.40f && v < 1.60f)) ok[0] = 0;
    }
    const float* pf = (const float*)x;
    { float v = pf[t]; if (!(v > 0.40f && v < 1.60f)) ok[1] = 0; }
    const double* pd = (const double*)x;
    { double v = pd[t]; if (!(v > 0.40 && v < 1.60)) ok[2] = 0; }
    __syncthreads();
    if (t == 0) ws[SC_DT] = ok[0] ? 0.0 : (ok[1] ? 1.0 : 2.0);
}

// ---------------- small vector stage (1 block) ----------------
__global__ __launch_bounds__(256) void k_small(
    const void* xin, const void* Ar, const void* Ai,
    const void* cAr, const void* cAi,
    double* ws, float* out)
{
    __shared__ double xs[256], twc[256], tws[256], ur[256], ui[256], red[256];
    int t = threadIdx.x;
    int dt = (int)ws[SC_DT];
    double x = ldin(xin, t, dt);
    xs[t] = x;
    red[t] = log(x);
    double ang = -2.0 * PI_D * (double)t / 256.0;
    twc[t] = cos(ang); tws[t] = sin(ang);
    __syncthreads();
    for (int s = 128; s > 0; s >>= 1){ if (t < s) red[t] += red[t+s]; __syncthreads(); }
    double slog = red[0];
    __syncthreads();
    double dy = (t == 0) ? 0.0 : (x - xs[t-1]);
    double r = x * exp(-slog / 256.0);
    double unr = r * cos(dy), uni = r * sin(dy);
    ur[t] = unr; ui[t] = uni;
    ws[W_UNIT_RE + t] = unr; ws[W_UNIT_IM + t] = uni;
    __syncthreads();
    double fr = 0.0, fi = 0.0;
    for (int n = 0; n < 256; n++){
        int m = (t * n) & 255;
        double c = twc[m], s = tws[m];
        fr += ur[n]*c - ui[n]*s;
        fi += ur[n]*s + ui[n]*c;
    }
    red[t] = fr; __syncthreads();
    for (int s = 128; s > 0; s >>= 1){ if (t < s) red[t] += red[t+s]; __syncthreads(); }
    double sr = red[0]; __syncthreads();
    red[t] = fi; __syncthreads();
    for (int s = 128; s > 0; s >>= 1){ if (t < s) red[t] += red[t+s]; __syncthreads(); }
    double si = red[0];
    double den = sr*sr + si*si;
    double cr = (fr*sr + fi*si) / den, ci = (fi*sr - fr*si) / den;
    ws[W_C_RE + t] = cr; ws[W_C_IM + t] = ci;
    double ar = ldin(Ar, t, dt), ai = ldin(Ai, t, dt);
    double car = ldin(cAr, t, dt), cai = ldin(cAi, t, dt);
    double pr = ar*unr - ai*uni, pi = ar*uni + ai*unr;
    double qr = car*pr + cai*pi, qi = car*pi - cai*pr;
    out[t] = (float)(x + atan2(qi, qr));
    double ldr = 0.5 * log((qr*qr + qi*qi) / (unr*unr + uni*uni));
    double ldi = atan2(qi, qr) - atan2(uni, unr);
    ws[W_LD_RE + t] = ldr; ws[W_LD_IM + t] = ldi;
}

// ---------------- build Ew and new_uw (fp64 planes) ----------------
__global__ __launch_bounds__(256) void k_build_mats(
    const void* Ewr, const void* Ewi, const void* uwr, const void* uwi, double* ws)
{
    int ij = blockIdx.x * 256 + threadIdx.x;
    int i = ij >> 8, j = ij & 255;
    int dt = (int)ws[SC_DT];
    double* EW = ws + MAT0 + (size_t)S_EW * MATD;
    EW[ij] = ldin(Ewr, ij, dt); EW[NN + ij] = ldin(Ewi, ij, dt);
    double* U = ws + MAT0 + (size_t)S_NUW * MATD;
    if (i == 0){ U[ij] = ws[W_LD_RE + j]; U[NN + ij] = ws[W_LD_IM + j]; }
    else { int src = (i-1)*256 + j; U[ij] = ldin(uwr, src, dt); U[NN + ij] = ldin(uwi, src, dt); }
}

// ---------------- norms: ws[idx]=n1, ws[idx+1]=ninf, ws[SC_NUINV]=1/(n1*ninf) ----
__global__ __launch_bounds__(256) void k_norm1inf(const double* M, double* ws, int idx)
{
    __shared__ double cs[256], rs[256];
    int t = threadIdx.x;
    double c = 0.0, r = 0.0;
    for (int i = 0; i < 256; i++){
        c += fabs(M[i*256 + t]) + fabs(M[NN + i*256 + t]);
        r += fabs(M[t*256 + i]) + fabs(M[NN + t*256 + i]);
    }
    cs[t] = c; rs[t] = r; __syncthreads();
    for (int s = 128; s > 0; s >>= 1){
        if (t < s){ cs[t] = fmax(cs[t], cs[t+s]); rs[t] = fmax(rs[t], rs[t+s]); }
        __syncthreads();
    }
    if (t == 0){
        ws[idx] = cs[0]; ws[idx+1] = rs[0];
        ws[SC_NUINV] = 1.0 / (cs[0] * rs[0]);
    }
}

// Frobenius^2 -> ws[14]
__global__ __launch_bounds__(256) void k_fro(const double* M, double* ws)
{
    __shared__ double red[256];
    int t = threadIdx.x;
    double s = 0.0;
    for (int i = 0; i < 256; i++){
        double a = M[i*256 + t], b = M[NN + i*256 + t];
        s += a*a + b*b;
    }
    red[t] = s; __syncthreads();
    for (int k = 128; k > 0; k >>= 1){ if (t < k) red[t] += red[t+k]; __syncthreads(); }
    if (t == 0) ws[14] = red[0];
}

// rigorous sigma_max upper bound: min( sqrt(n1*ninf), ||S||_F )
__global__ void k_snorm(double* ws)
{
    double b1 = sqrt(ws[12] * ws[13]);
    double b2 = sqrt(ws[14]);
    ws[SC_NORMS2] = fmin(b1, b2);
}

// ---------------- complex GEMM (used by expm chain + powers) ----------------
// C = alpha*preA(A)*preB(B) + beta*D + gamma*I
// preA: 0 none, 1 conj, 2 (A-I).  preB: 0 none, 1 (2I-B).
// fm: 0 normal; 1 expm-squaring (round>ws[SC_EXPM_S] -> copy A)
__global__ __launch_bounds__(256) void k_zgemm(
    const double* __restrict__ Ab, const double* __restrict__ Bb,
    double* __restrict__ Cb, const double* __restrict__ Db,
    int preA, int preB, double alpha, double beta, double gamma,
    double* __restrict__ ws, int fm, int round,
    long sA, long sB, long sC)
{
    int z = blockIdx.z;
    const double* A = Ab + (size_t)z * sA;
    const double* B = Bb + (size_t)z * sB;
    double* C = Cb + (size_t)z * sC;
    int tx = threadIdx.x & 15, ty = threadIdx.x >> 4;
    int row = blockIdx.y * 16 + ty, col = blockIdx.x * 16 + tx;
    if (fm == 1 && round > (int)ws[SC_EXPM_S]){
        C[row*256 + col] = A[row*256 + col];
        C[NN + row*256 + col] = A[NN + row*256 + col];
        return;
    }
    __shared__ double Asr[16][17], Asi[16][17], Bsr[16][17], Bsi[16][17];
    double cr = 0.0, ci = 0.0;
    for (int k0 = 0; k0 < 256; k0 += 16){
        int ac = k0 + tx;
        double a_re = A[row*256 + ac], a_im = A[NN + row*256 + ac];
        if (preA == 1) a_im = -a_im;
        else if (preA == 2){ if (row == ac) a_re -= 1.0; }
        int br = k0 + ty;
        double b_re = B[br*256 + col], b_im = B[NN + br*256 + col];
        if (preB == 1){ b_re = ((br == col) ? 2.0 : 0.0) - b_re; b_im = -b_im; }
        Asr[ty][tx] = a_re; Asi[ty][tx] = a_im;
        Bsr[ty][tx] = b_re; Bsi[ty][tx] = b_im;
        __syncthreads();
        #pragma unroll
        for (int kk = 0; kk < 16; kk++){
            double xr = Asr[ty][kk], xi = Asi[ty][kk];
            double yr = Bsr[kk][tx], yi = Bsi[kk][tx];
            cr += xr*yr - xi*yi;
            ci += xr*yi + xi*yr;
        }
        __syncthreads();
    }
    double outr = alpha * cr, outi = alpha * ci;
    if (Db){ outr += beta * Db[row*256 + col]; outi += beta * Db[NN + row*256 + col]; }
    if (row == col) outr += gamma;
    C[row*256 + col] = outr;
    C[NN + row*256 + col] = outi;
}

// ---- elementwise: C = a1*f1*X1 + a2*X2 + a3*X3 + a4*X4 + g*I ; mode1: f1=expm scale
__global__ __launch_bounds__(256) void k_combine(double* ws, int dst,
    int s1, int s2, int s3, int s4,
    double a1, double a2, double a3, double a4, double g, int mode)
{
    int ij = blockIdx.x * 256 + threadIdx.x;
    int i = ij >> 8, j = ij & 255;
    double f1 = (mode == 1) ? ws[SC_EXPM_SCALE] : 1.0;
    double* C = ws + MAT0 + (size_t)dst * MATD;
    double r = 0.0, m = 0.0;
    if (s1 >= 0){ const double* X = ws + MAT0 + (size_t)s1 * MATD; r += a1*f1*X[ij]; m += a1*f1*X[NN+ij]; }
    if (s2 >= 0){ const double* X = ws + MAT0 + (size_t)s2 * MATD; r += a2*X[ij]; m += a2*X[NN+ij]; }
    if (s3 >= 0){ const double* X = ws + MAT0 + (size_t)s3 * MATD; r += a3*X[ij]; m += a3*X[NN+ij]; }
    if (s4 >= 0){ const double* X = ws + MAT0 + (size_t)s4 * MATD; r += a4*X[ij]; m += a4*X[NN+ij]; }
    if (i == j) r += g;
    C[ij] = r; C[NN + ij] = m;
}

__global__ void k_expm_prep(double* ws)
{
    if (threadIdx.x == 0 && blockIdx.x == 0){
        double n1 = ws[8];
        int s = 0;
        if (n1 > 0.5){
            s = (int)ceil(log2(n1 / 0.5));
            if (s < 0) s = 0; if (s > 10) s = 10;
        }
        ws[SC_EXPM_S] = (double)s;
        ws[SC_EXPM_SCALE] = ldexp(1.0, -s);
    }
}

// ================= cooperative logm chain =================
// grid 256 blocks x 256 threads; block b handles output tile (b>>4, b&15) in GEMM
// phases and row/col b in norm phases. All control flow uniform across blocks.
__global__ __launch_bounds__(256, 1) void k_chain(double* ws)
{
    cg::grid_group grid = cg::this_grid();
    const int t  = threadIdx.x;
    const int tx = t & 15, ty = t >> 4;
    const int b  = blockIdx.x;
    const int bx = b & 15, by = b >> 4;
    const int row = by*16 + ty, col = bx*16 + tx;
    const int ij = row*256 + col;

    __shared__ double Asr[16][17], Asi[16][17], Bsr[16][17], Bsi[16][17];
    __shared__ double red[256];

    auto MPd = [&](int s)->double*{ return ws + MAT0 + (size_t)s * MATD; };

    auto bsum = [&](double v)->double {
        red[t] = v; __syncthreads();
        for (int s = 128; s > 0; s >>= 1){ if (t < s) red[t] += red[t+s]; __syncthreads(); }
        double r = red[0]; __syncthreads();
        return r;
    };
    auto gmax = [&](int base)->double {   // identical in all blocks (same data, same order)
        red[t] = ws[base + t]; __syncthreads();
        for (int s = 128; s > 0; s >>= 1){ if (t < s) red[t] = fmax(red[t], red[t+s]); __syncthreads(); }
        double r = red[0]; __syncthreads();
        return r;
    };

    auto zmm = [&](const double* A, const double* B, int preA, int preB,
                   double& cr, double& ci){
        cr = 0.0; ci = 0.0;
        for (int k0 = 0; k0 < 256; k0 += 16){
            int ac = k0 + tx;
            double a_re = A[row*256 + ac], a_im = A[NN + row*256 + ac];
            if (preA == 2){ if (row == ac) a_re -= 1.0; }
            int br = k0 + ty;
            double b_re = B[br*256 + col], b_im = B[NN + br*256 + col];
            if (preB == 1){ b_re = ((br == col) ? 2.0 : 0.0) - b_re; b_im = -b_im; }
            Asr[ty][tx] = a_re; Asi[ty][tx] = a_im;
            Bsr[ty][tx] = b_re; Bsi[ty][tx] = b_im;
            __syncthreads();
            #pragma unroll
            for (int kk = 0; kk < 16; kk++){
                double xr = Asr[ty][kk], xi = Asi[ty][kk];
                double yr = Bsr[kk][tx], yi = Bsi[kk][tx];
                cr += xr*yr - xi*yi;
                ci += xr*yi + xi*yr;
            }
            __syncthreads();
        }
    };

    // col/row sums of |M| (col b, row b), colsum of |M-I|; zero NS residual bufs
    auto norm_phase = [&](const double* M){
        double mr = M[t*256 + b], mi = M[NN + t*256 + b];
        double c  = fabs(mr) + fabs(mi);
        double cm = fabs(mr - ((t == b) ? 1.0 : 0.0)) + fabs(mi);
        double rr = fabs(M[b*256 + t]) + fabs(M[NN + b*256 + t]);
        double sc = bsum(c), scm = bsum(cm), sr = bsum(rr);
        if (t == 0){
            ws[CS_M + b] = sc; ws[CS_MI + b] = scm; ws[RS_M + b] = sr;
            ws[RS_A + b] = 0.0; ws[RS_B + b] = 0.0;
        }
    };
    auto normI_phase = [&](const double* M){
        double c  = fabs(M[t*256 + b]) + fabs(M[NN + t*256 + b]);
        double rr = fabs(M[b*256 + t]) + fabs(M[NN + b*256 + t]);
        double sc = bsum(c), sr = bsum(rr);
        if (t == 0){ ws[CS_I + b] = sc; ws[RS_I + b] = sr; }
    };
    auto cold_phase = [&](const double* M, double* X, double nu){
        X[ij]      =  M[col*256 + row] * nu;
        X[NN + ij] = -M[NN + col*256 + row] * nu;
        if (t == 0){ ws[RS_A + b] = 0.0; ws[RS_B + b] = 0.0; }
    };
    // T = M*X, accumulate colsums of |T - I| into ws[cur..], zero ws[oth..]
    auto t_phase = [&](const double* M, const double* X, double* T, int cur, int oth){
        double cr, ci; zmm(M, X, 0, 0, cr, ci);
        T[ij] = cr; T[NN + ij] = ci;
        double e = fabs(cr - ((row == col) ? 1.0 : 0.0)) + fabs(ci);
        Asr[ty][tx] = e; __syncthreads();
        if (ty == 0){
            double s = 0.0;
            #pragma unroll
            for (int q = 0; q < 16; q++) s += Asr[q][tx];
            atomicAdd(&ws[cur + (bx*16 + tx)], s);
        }
        if (t == 0) ws[oth + b] = 0.0;
        __syncthreads();
    };
    auto x_phase = [&](const double* X, const double* T, double* Xo){
        double cr, ci; zmm(X, T, 0, 1, cr, ci);
        Xo[ij] = cr; Xo[NN + ij] = ci;
    };

    int invslot = S_X;
    bool haveWarm = false;

    // NS inverse of slot mslot -> invslot. Warm start from previous inverse with
    // rigorous fallback (n1 residual >= 0.9 -> cold restart X0 = M^H/(n1*ninf)).
    auto inv_dev = [&](int mslot, int cap, double nmprod){
        bool warm = haveWarm;
        int xc = warm ? invslot : S_X;
        int xo = (xc == S_X) ? S_X2 : S_X;
        if (!warm){
            cold_phase(MPd(mslot), MPd(xc), 1.0 / nmprod);
            grid.sync();
        }
        for (int k = 0; k < cap; k++){
            int cur = (k & 1) ? RS_B : RS_A;
            int oth = (k & 1) ? RS_A : RS_B;
            t_phase(MPd(mslot), MPd(xc), MPd(S_T), cur, oth);
            grid.sync();
            double r = gmax(cur);          // n1(I - M X), uniform
            if (k == 0 && warm && r >= 0.9){
                grid.sync();               // all readers done before cold writes
                cold_phase(MPd(mslot), MPd(xc), 1.0 / nmprod);
                grid.sync();
                warm = false; k = -1; continue;
            }
            if (r < 1e-11) break;
            x_phase(MPd(xc), MPd(S_T), MPd(xo));
            grid.sync();
            int tmp = xc; xc = xo; xo = tmp;
        }
        invslot = xc;
        haveWarm = true;
    };

    const int DBCAP[6] = {22, 12, 10, 10, 8, 8};
    const int NSCAP[6] = {44, 24, 20, 18, 16, 16};
    int yc = S_Y, yo = S_Y2;

    for (int st = 0; st < 6; st++){
        {   // stage init: M = A (and stage 0: Y = A)
            const double* A = MPd(st == 0 ? S_EW : yc);
            double* Md = MPd(S_M);
            double vr = A[ij], vi = A[NN + ij];
            Md[ij] = vr; Md[NN + ij] = vi;
            if (st == 0){ double* Yd = MPd(S_Y); Yd[ij] = vr; Yd[NN + ij] = vi; }
        }
        grid.sync();
        int mc = S_M, mo = S_M2;
        for (int it = 0; it < DBCAP[st]; it++){
            norm_phase(MPd(mc));
            grid.sync();
            double n1m = gmax(CS_M), nfm = gmax(RS_M), nmi = gmax(CS_MI);
            if (nmi < 1e-10) break;                 // M -> I: stage converged
            inv_dev(mc, NSCAP[st], n1m * nfm);
            normI_phase(MPd(invslot));
            grid.sync();
            double n1i = gmax(CS_I), nfi = gmax(RS_I);
            double mu = pow((n1i * nfi) / (n1m * nfm), 0.125);
            mu = fmin(fmax(mu, 0.125), 8.0);
            {   // fused: Y' = 0.5(mu Y + mu^-1 Y M^-1);  M' = 0.5I + 0.25(mu^2 M + mu^-2 M^-1)
                const double* Y = MPd(yc); const double* IY = MPd(invslot); const double* M = MPd(mc);
                double* Yo = MPd(yo); double* Mo = MPd(mo);
                double cr, ci; zmm(Y, IY, 0, 0, cr, ci);
                double hmu = 0.5*mu, hmi = 0.5/mu;
                Yo[ij]      = hmu*Y[ij]      + hmi*cr;
                Yo[NN + ij] = hmu*Y[NN + ij] + hmi*ci;
                double q2 = 0.25*mu*mu, qi2 = 0.25/(mu*mu);
                Mo[ij]      = q2*M[ij]      + qi2*IY[ij] + ((row == col) ? 0.5 : 0.0);
                Mo[NN + ij] = q2*M[NN + ij] + qi2*IY[NN + ij];
            }
            grid.sync();
            int tp = mc; mc = mo; mo = tp;
            tp = yc; yc = yo; yo = tp;
        }
    }

    // Cayley: W = (B - I)(B + I)^-1 , B = Ew^(1/64) in slot yc
    {
        const double* Bm = MPd(yc); double* C = MPd(S_M);
        C[ij] = Bm[ij] + ((row == col) ? 1.0 : 0.0);
        C[NN + ij] = Bm[NN + ij];
    }
    grid.sync();
    norm_phase(MPd(S_M));
    grid.sync();
    {
        double n1c = gmax(CS_M), nfc = gmax(RS_M);
        inv_dev(S_M, 24, n1c * nfc);
    }
    { double cr, ci; zmm(MPd(yc), MPd(invslot), 2, 0, cr, ci);
      double* W = MPd(S_W); W[ij] = cr; W[NN + ij] = ci; }
    grid.sync();
    { double cr, ci; zmm(MPd(S_W), MPd(S_W), 0, 0, cr, ci);
      double* V = MPd(S_V); V[ij] = cr; V[NN + ij] = ci; }
    grid.sync();
    { double* P = MPd(S_G);
      P[ij] = (row == col) ? (1.0/39.0) : 0.0; P[NN + ij] = 0.0; }
    grid.sync();
    int gc = S_G, go = S_G2;
    for (int j = 18; j >= 0; j--){   // artanh(W) = W * sum_{j=0}^{19} V^j/(2j+1), deg 39
        double cr, ci; zmm(MPd(S_V), MPd(gc), 0, 0, cr, ci);
        double* G = MPd(go);
        G[ij] = cr + ((row == col) ? 1.0/(double)(2*j + 1) : 0.0);
        G[NN + ij] = ci;
        grid.sync();
        int tmp = gc; gc = go; go = tmp;
    }
    { double cr, ci; zmm(MPd(S_W), MPd(gc), 0, 0, cr, ci);
      double* L = MPd(S_LAT); L[ij] = cr; L[NN + ij] = ci; }
    grid.sync();
    {   // S = 128 * conj(LAT - LAT^T)
        const double* L = MPd(S_LAT); double* S = MPd(PBASE);
        S[ij]      =  128.0 * (L[ij] - L[col*256 + row]);
        S[NN + ij] = -128.0 * (L[NN + ij] - L[NN + col*256 + row]);
    }
}

// theta per u (rigorous upper bound); theta>4 -> scaling+squaring pool
__global__ __launch_bounds__(256) void k_theta_pool(double* ws)
{
    __shared__ double th[256]; __shared__ int rk[256];
    int t = threadIdx.x;
    double nS = ws[SC_NORMS2];
    double cr = ws[W_C_RE + t], ci = ws[W_C_IM + t];
    th[t] = sqrt(cr*cr + ci*ci) * nS;
    __syncthreads();
    int r = 0;
    for (int v = 0; v < 256; v++){
        if (th[v] > th[t] || (th[v] == th[t] && v < t)) r++;
    }
    rk[t] = r;
    __syncthreads();
    if (t == 0){
        int cnt = 0;
        for (int u = 0; u < 256; u++){
            double s = 0.0; int slot = -1;
            if (th[u] > 4.0 && rk[u] < NPOOL){
                double e = ceil(log2(th[u] / 4.0));
                if (e < 1.0) e = 1.0; if (e > 12.0) e = 12.0;
                s = e; slot = cnt;
                ws[W_SLOTU + cnt] = (double)u;
                cnt++;
            }
            ws[W_SU + u] = s;
            ws[W_SLOT + u] = (double)slot;
        }
        for (int k = cnt; k < NPOOL; k++) ws[W_SLOTU + k] = -1.0;
    }
}

// weights w[u][k] = (c_u / 2^{s_u})^k / k!
__global__ __launch_bounds__(256) void k_weights(double* ws)
{
    int u = threadIdx.x;
    double sc = ldexp(1.0, -(int)ws[W_SU + u]);
    double cr = ws[W_C_RE + u] * sc, ci = ws[W_C_IM + u] * sc;
    double wr = 1.0, wi = 0.0;
    ws[W_W + (u*33)*2] = 1.0; ws[W_W + (u*33)*2 + 1] = 0.0;
    for (int k = 1; k <= 32; k++){
        double inv = 1.0 / (double)k;
        double nr = (wr*cr - wi*ci) * inv, ni = (wr*ci + wi*cr) * inv;
        wr = nr; wi = ni;
        ws[W_W + (u*33 + k)*2] = wr;
        ws[W_W + (u*33 + k)*2 + 1] = wi;
    }
}

// exp_tens[u] = sum_k w[u][k] S^k -> f32 out (non-pooled, pass 0) or fp64 pool base
__global__ __launch_bounds__(256) void k_combo(double* ws, float* out, long off_ex, int f,
                                               int pass, int K)
{
    __shared__ double wre[16][33], wim[16][33];
    __shared__ int anywork;
    int t = threadIdx.x;
    int row = blockIdx.x, ug = blockIdx.y;
    if (t == 0) anywork = (pass == 0) ? 1 : 0;
    __syncthreads();
    if (pass > 0 && t < 16){
        int u = ug*16 + t;
        int slot = (int)ws[W_SLOT + u];
        int phys = slot - pass * K;
        if (slot >= 0 && phys >= 0 && phys < K) anywork = 1;
    }
    __syncthreads();
    if (!anywork) return;
    for (int i = t; i < 16*33; i += 256){
        int g = i / 33, k = i % 33;
        int u = ug*16 + g;
        wre[g][k] = ws[W_W + (u*33 + k)*2];
        wim[g][k] = ws[W_W + (u*33 + k)*2 + 1];
    }
    __syncthreads();
    int j = t, ij = row*256 + j;
    double ar[16], ai[16];
    #pragma unroll
    for (int g = 0; g < 16; g++){
        ar[g] = (row == j) ? wre[g][0] : 0.0;
        ai[g] = (row == j) ? wim[g][0] : 0.0;
    }
    for (int k = 1; k <= 32; k++){
        const double* SP = ws + MAT0 + (size_t)(PBASE + k - 1) * MATD;
        double sre = SP[ij], sim = SP[NN + ij];
        #pragma unroll
        for (int g = 0; g < 16; g++){
            ar[g] += wre[g][k]*sre - wim[g][k]*sim;
            ai[g] += wre[g][k]*sim + wim[g][k]*sre;
        }
    }
    for (int g = 0; g < 16; g++){
        int u = ug*16 + g;
        int slot = (int)ws[W_SLOT + u];
        if (slot >= 0){
            int phys = slot - pass * K;
            if (phys >= 0 && phys < K){
                double* P = ws + MAT0 + (size_t)(POOL0 + phys) * MATD;
                P[ij] = ar[g]; P[NN + ij] = ai[g];
            }
        } else if (pass == 0){
            long base = off_ex + (long)u * NN * f + (long)ij * f;
            out[base] = (float)ar[g];
            if (f == 2) out[base + 1] = (float)ai[g];
        }
    }
}

// pool squaring: virtual slot = pass*K + z; square only if round <= s_u
__global__ __launch_bounds__(256) void k_pool_sq(double* ws, int round, int pass, int K)
{
    int z = blockIdx.z;
    int vs = pass * K + z;
    int u = (vs < NPOOL) ? (int)ws[W_SLOTU + vs] : -1;
    if (u < 0) return;
    if (round > (int)ws[W_SU + u]) return;
    const double* A = ws + MAT0 + (size_t)(POOL0 + ((round & 1) ? 0 : K) + z) * MATD;
    double* C = ws + MAT0 + (size_t)(POOL0 + ((round & 1) ? K : 0) + z) * MATD;
    int tx = threadIdx.x & 15, ty = threadIdx.x >> 4;
    int row = blockIdx.y*16 + ty, col = blockIdx.x*16 + tx;
    __shared__ double Asr[16][17], Asi[16][17], Bsr[16][17], Bsi[16][17];
    double cr = 0.0, ci = 0.0;
    for (int k0 = 0; k0 < 256; k0 += 16){
        Asr[ty][tx] = A[row*256 + k0 + tx];
        Asi[ty][tx] = A[NN + row*256 + k0 + tx];
        Bsr[ty][tx] = A[(k0 + ty)*256 + col];
        Bsi[ty][tx] = A[NN + (k0 + ty)*256 + col];
        __syncthreads();
        #pragma unroll
        for (int kk = 0; kk < 16; kk++){
            double xr = Asr[ty][kk], xi = Asi[ty][kk];
            double yr = Bsr[kk][tx], yi = Bsi[kk][tx];
            cr += xr*yr - xi*yi;
            ci += xr*yi + xi*yr;
        }
        __syncthreads();
    }
    C[row*256 + col] = cr;
    C[NN + row*256 + col] = ci;
}

__global__ __launch_bounds__(256) void k_pool_out(const double* ws, float* out, long off_ex,
                                                  int f, int pass, int K)
{
    int z = blockIdx.y;
    int vs = pass * K + z;
    int u = (vs < NPOOL) ? (int)ws[W_SLOTU + vs] : -1;
    if (u < 0) return;
    int su = (int)ws[W_SU + u];
    int ij = blockIdx.x * 256 + threadIdx.x;
    const double* P = ws + MAT0 + (size_t)(POOL0 + ((su & 1) ? K : 0) + z) * MATD;
    long base = off_ex + (long)u * NN * f + (long)ij * f;
    out[base] = (float)P[ij];
    if (f == 2) out[base + 1] = (float)P[NN + ij];
}

__global__ __launch_bounds__(256) void k_cast_out(const double* ws, int slot, float* out, long off, int f)
{
    int ij = blockIdx.x * 256 + threadIdx.x;
    const double* P = ws + MAT0 + (size_t)slot * MATD;
    out[off + (long)ij * f] = (float)P[ij];
    if (f == 2) out[off + (long)ij * f + 1] = (float)P[NN + ij];
}

// ============================ host ============================
extern "C" void kernel_launch(void* const* d_in, const int* in_sizes, int n_in,
                              void* d_out, int out_size, void* d_ws, size_t ws_size,
                              hipStream_t stream)
{
    double* ws = (double*)d_ws;
    float* out = (float*)d_out;

    int f = (out_size >= 33816832) ? 2 : 1;
    long off_ex = 256;
    long off_uw = off_ex + (long)f * 16777216L;
    long off_ew = off_uw + (long)f * 65536L;

    k_init<<<128, 256, 0, stream>>>(ws);
    k_detect<<<1, 64, 0, stream>>>(d_in[0], ws);
    k_small<<<1, 256, 0, stream>>>(d_in[0], d_in[1], d_in[2], d_in[3], d_in[4], ws, out);

    long slotsAvail = (long)(ws_size / 8 - MAT0) / MATD;
    if (slotsAvail < POOL0 + 32) return;   // need >= 52 work slots + 16x2 pool (~88.3 MB)
    int K = (int)((slotsAvail - POOL0) / 2);
    if (K > NPOOL) K = NPOOL;
    if (K < 16) K = 16;
    int P = (NPOOL + K - 1) / K;

    auto MP = [&](int s){ return ws + MAT0 + (size_t)s * MATD; };
    auto ZG = [&](int a, int b, int c, int preA, int preB, double al, double be,
                  int d, double ga, int fm, int round){
        k_zgemm<<<dim3(16,16,1), 256, 0, stream>>>(MP(a), MP(b), MP(c),
            d >= 0 ? MP(d) : nullptr, preA, preB, al, be, ga, ws,
            fm, round, 0L, 0L, 0L);
    };
    auto GEMM = [&](int a, int b, int c, int preA, int preB, double al, double be, int d, double ga){
        ZG(a, b, c, preA, preB, al, be, d, ga, 0, 0);
    };

    k_build_mats<<<256, 256, 0, stream>>>(d_in[5], d_in[6], d_in[7], d_in[8], ws);
    k_cast_out<<<256, 256, 0, stream>>>(ws, S_NUW, out, off_uw, f);

    // -------- expm(new_uw): scaling + Paterson-Stockmeyer deg-16 Taylor + squarings ----
    static const double INVF[17] = {
        1.0, 1.0, 0.5, 1.0/6.0, 1.0/24.0, 1.0/120.0, 1.0/720.0, 1.0/5040.0,
        1.0/40320.0, 1.0/362880.0, 1.0/3628800.0, 1.0/39916800.0, 1.0/479001600.0,
        1.0/6227020800.0, 1.0/87178291200.0, 1.0/1307674368000.0, 1.0/20922789888000.0 };
    k_norm1inf<<<1, 256, 0, stream>>>(MP(S_NUW), ws, 8);
    k_expm_prep<<<1, 64, 0, stream>>>(ws);
    k_combine<<<256, 256, 0, stream>>>(ws, S_LAT, S_NUW, -1, -1, -1, 1.0, 0, 0, 0, 0.0, 1); // T = 2^-s NUW
    GEMM(S_LAT, S_LAT, S_T2, 0, 0, 1.0, 0.0, -1, 0.0);
    GEMM(S_T2, S_LAT, S_T3, 0, 0, 1.0, 0.0, -1, 0.0);
    GEMM(S_T2, S_T2, S_T4, 0, 0, 1.0, 0.0, -1, 0.0);
    k_combine<<<256, 256, 0, stream>>>(ws, S_E1, -1, -1, -1, -1, 0, 0, 0, 0, INVF[16], 0);
    for (int b = 3; b >= 0; b--){
        GEMM(S_T4, S_E1, S_E2, 0, 0, 1.0, 0.0, -1, 0.0);
        k_combine<<<256, 256, 0, stream>>>(ws, S_E1, S_E2, S_LAT, S_T2, S_T3,
            1.0, INVF[4*b+1], INVF[4*b+2], INVF[4*b+3], INVF[4*b], 0);
    }
    for (int r = 1; r <= 10; r++){
        int src = (r & 1) ? S_E1 : S_E2, dst = (r & 1) ? S_E2 : S_E1;
        ZG(src, src, dst, 0, 0, 1.0, 0.0, -1, 0.0, 1, r);
    }
    GEMM(S_EW, S_E1, S_M2, 1, 0, 1.0, 0.0, -1, 0.0);   // new_Ew = conj(Ew) expm(new_uw)
    k_cast_out<<<256, 256, 0, stream>>>(ws, S_M2, out, off_ew, f);

    // -------- logm(Ew): single cooperative kernel (6 scaled DB sqrt stages,
    //          warm-started residual-gated NS inverses, Cayley + deg-39 artanh) ----
    {
        void* chainArgs[] = { (void*)&ws };
        hipLaunchCooperativeKernel((const void*)k_chain, dim3(256), dim3(256),
                                   chainArgs, 0, stream);
    }

    // -------- batched exp_tens = expm(c_u S): shared powers + pooled squaring --------
    k_norm1inf<<<1, 256, 0, stream>>>(MP(PBASE), ws, 12);   // rigorous norm bound inputs
    k_fro<<<1, 256, 0, stream>>>(MP(PBASE), ws);
    k_snorm<<<1, 1, 0, stream>>>(ws);
    k_theta_pool<<<1, 256, 0, stream>>>(ws);
    k_weights<<<1, 256, 0, stream>>>(ws);
    for (int m = 1; m < 32; m *= 2){
        int cnt = (m < 32 - m) ? m : (32 - m);
        k_zgemm<<<dim3(16,16,cnt), 256, 0, stream>>>(MP(PBASE + m - 1), MP(PBASE), MP(PBASE + m),
            nullptr, 0, 0, 1.0, 0.0, 0.0, ws, 0, 0, 0L, MATD, MATD);
    }
    for (int p = 0; p < P; p++){
        k_combo<<<dim3(256,16), 256, 0, stream>>>(ws, out, off_ex, f, p, K);
        for (int r = 1; r <= 12; r++)
            k_pool_sq<<<dim3(16,16,K), 256, 0, stream>>>(ws, r, p, K);
        k_pool_out<<<dim3(256,K), 256, 0, stream>>>(ws, out, off_ex, f, p, K);
    }
}

// Round 7
// 39764.441 us; speedup vs baseline: 1.1915x; 1.1915x over previous
//
#include <hip/hip_runtime.h>
#include <hip/hip_bf16.h>
#include <hip/hip_cooperative_groups.h>
#include <math.h>

namespace cg = cooperative_groups;

#define NN 65536
#define MATD 131072L   // doubles per complex matrix (re plane + im plane)
#define MAT0 32768L    // header size in doubles

// ws header offsets (doubles)
#define SC_DT 0
#define SC_NUINV 3
#define SC_EXPM_S 4
#define SC_EXPM_SCALE 5
#define SC_NORMS2 6
// 8,9: n1,ninf of M ; 12,13: n1,ninf of S ; 14: F^2 of S
#define W_UNIT_RE 64
#define W_UNIT_IM 320
#define W_C_RE 576
#define W_C_IM 832
#define W_LD_RE 1088
#define W_LD_IM 1344
#define W_SU 1600
#define W_SLOT 1856
#define W_SLOTU 2112        // 256 entries -> ends 2368
#define W_W 2432            // 256*33*2 doubles -> ends 19328
// cooperative-chain scratch (zeroed by k_init)
#define RS_A 22528
#define RS_B 22784
#define CS_M 23040
#define RS_M 23296
#define CS_MI 23552
#define CS_I 23808
#define RS_I 24064
#define NPOOL 256           // virtual pool capacity (every unit can be pooled)

// matrix slots
#define S_EW 0
#define S_NUW 1
#define S_LAT 2
#define S_T2 3
#define S_T3 4
#define S_T4 5
#define S_E1 6
#define S_E2 7
#define S_M 8
#define S_M2 9
#define S_Y 10
#define S_Y2 11
#define S_IY 12
#define S_X 13
#define S_X2 14
#define S_T 15
#define S_W 16
#define S_V 17
#define S_G 18
#define S_G2 19
#define PBASE 20            // S^k at PBASE+k-1, k=1..32 -> 20..51
#define POOL0 52            // physical pool: A at 52..52+K-1, B at 52+K..52+2K-1

#define PI_D 3.14159265358979323846

__device__ inline double ldin(const void* p, int i, int dt){
    if (dt == 0) return (double)__bfloat162float(((const __hip_bfloat16*)p)[i]);
    if (dt == 1) return (double)((const float*)p)[i];
    return ((const double*)p)[i];
}

// ---------------- init: zero header ----------------
__global__ __launch_bounds__(256) void k_init(double* ws){
    ws[blockIdx.x * 256 + threadIdx.x] = 0.0;   // grid 128 -> 32768
}

// ---------------- input dtype detection ----------------
__global__ __launch_bounds__(64) void k_detect(const void* x, double* ws){
    __shared__ int ok[3];
    int t = threadIdx.x;
    if (t < 3) ok[t] = 1;
    __syncthreads();
    const __hip_bfloat16* pb = (const __hip_bfloat16*)x;
    for (int k = t; k < 256; k += 64){
        float v = __bfloat162float(pb[k]);
        if (!(v > 0.40f && v < 1.60f)) ok[0] = 0;
    }
    const float* pf = (const float*)x;
    { float v = pf[t]; if (!(v > 0.40f && v < 1.60f)) ok[1] = 0; }
    const double* pd = (const double*)x;
    { double v = pd[t]; if (!(v > 0.40 && v < 1.60)) ok[2] = 0; }
    __syncthreads();
    if (t == 0) ws[SC_DT] = ok[0] ? 0.0 : (ok[1] ? 1.0 : 2.0);
}

// ---------------- small vector stage (1 block) ----------------
__global__ __launch_bounds__(256) void k_small(
    const void* xin, const void* Ar, const void* Ai,
    const void* cAr, const void* cAi,
    double* ws, float* out)
{
    __shared__ double xs[256], twc[256], tws[256], ur[256], ui[256], red[256];
    int t = threadIdx.x;
    int dt = (int)ws[SC_DT];
    double x = ldin(xin, t, dt);
    xs[t] = x;
    red[t] = log(x);
    double ang = -2.0 * PI_D * (double)t / 256.0;
    twc[t] = cos(ang); tws[t] = sin(ang);
    __syncthreads();
    for (int s = 128; s > 0; s >>= 1){ if (t < s) red[t] += red[t+s]; __syncthreads(); }
    double slog = red[0];
    __syncthreads();
    double dy = (t == 0) ? 0.0 : (x - xs[t-1]);
    double r = x * exp(-slog / 256.0);
    double unr = r * cos(dy), uni = r * sin(dy);
    ur[t] = unr; ui[t] = uni;
    ws[W_UNIT_RE + t] = unr; ws[W_UNIT_IM + t] = uni;
    __syncthreads();
    double fr = 0.0, fi = 0.0;
    for (int n = 0; n < 256; n++){
        int m = (t * n) & 255;
        double c = twc[m], s = tws[m];
        fr += ur[n]*c - ui[n]*s;
        fi += ur[n]*s + ui[n]*c;
    }
    red[t] = fr; __syncthreads();
    for (int s = 128; s > 0; s >>= 1){ if (t < s) red[t] += red[t+s]; __syncthreads(); }
    double sr = red[0]; __syncthreads();
    red[t] = fi; __syncthreads();
    for (int s = 128; s > 0; s >>= 1){ if (t < s) red[t] += red[t+s]; __syncthreads(); }
    double si = red[0];
    double den = sr*sr + si*si;
    double cr = (fr*sr + fi*si) / den, ci = (fi*sr - fr*si) / den;
    ws[W_C_RE + t] = cr; ws[W_C_IM + t] = ci;
    double ar = ldin(Ar, t, dt), ai = ldin(Ai, t, dt);
    double car = ldin(cAr, t, dt), cai = ldin(cAi, t, dt);
    double pr = ar*unr - ai*uni, pi = ar*uni + ai*unr;
    double qr = car*pr + cai*pi, qi = car*pi - cai*pr;
    out[t] = (float)(x + atan2(qi, qr));
    double ldr = 0.5 * log((qr*qr + qi*qi) / (unr*unr + uni*uni));
    double ldi = atan2(qi, qr) - atan2(uni, unr);
    ws[W_LD_RE + t] = ldr; ws[W_LD_IM + t] = ldi;
}

// ---------------- build Ew and new_uw (fp64 planes) ----------------
__global__ __launch_bounds__(256) void k_build_mats(
    const void* Ewr, const void* Ewi, const void* uwr, const void* uwi, double* ws)
{
    int ij = blockIdx.x * 256 + threadIdx.x;
    int i = ij >> 8, j = ij & 255;
    int dt = (int)ws[SC_DT];
    double* EW = ws + MAT0 + (size_t)S_EW * MATD;
    EW[ij] = ldin(Ewr, ij, dt); EW[NN + ij] = ldin(Ewi, ij, dt);
    double* U = ws + MAT0 + (size_t)S_NUW * MATD;
    if (i == 0){ U[ij] = ws[W_LD_RE + j]; U[NN + ij] = ws[W_LD_IM + j]; }
    else { int src = (i-1)*256 + j; U[ij] = ldin(uwr, src, dt); U[NN + ij] = ldin(uwi, src, dt); }
}

// ---------------- norms: ws[idx]=n1, ws[idx+1]=ninf, ws[SC_NUINV]=1/(n1*ninf) ----
__global__ __launch_bounds__(256) void k_norm1inf(const double* M, double* ws, int idx)
{
    __shared__ double cs[256], rs[256];
    int t = threadIdx.x;
    double c = 0.0, r = 0.0;
    for (int i = 0; i < 256; i++){
        c += fabs(M[i*256 + t]) + fabs(M[NN + i*256 + t]);
        r += fabs(M[t*256 + i]) + fabs(M[NN + t*256 + i]);
    }
    cs[t] = c; rs[t] = r; __syncthreads();
    for (int s = 128; s > 0; s >>= 1){
        if (t < s){ cs[t] = fmax(cs[t], cs[t+s]); rs[t] = fmax(rs[t], rs[t+s]); }
        __syncthreads();
    }
    if (t == 0){
        ws[idx] = cs[0]; ws[idx+1] = rs[0];
        ws[SC_NUINV] = 1.0 / (cs[0] * rs[0]);
    }
}

// Frobenius^2 -> ws[14]
__global__ __launch_bounds__(256) void k_fro(const double* M, double* ws)
{
    __shared__ double red[256];
    int t = threadIdx.x;
    double s = 0.0;
    for (int i = 0; i < 256; i++){
        double a = M[i*256 + t], b = M[NN + i*256 + t];
        s += a*a + b*b;
    }
    red[t] = s; __syncthreads();
    for (int k = 128; k > 0; k >>= 1){ if (t < k) red[t] += red[t+k]; __syncthreads(); }
    if (t == 0) ws[14] = red[0];
}

// rigorous sigma_max upper bound: min( sqrt(n1*ninf), ||S||_F )
__global__ void k_snorm(double* ws)
{
    double b1 = sqrt(ws[12] * ws[13]);
    double b2 = sqrt(ws[14]);
    ws[SC_NORMS2] = fmin(b1, b2);
}

// ---------------- complex GEMM (used by expm chain + powers) ----------------
__global__ __launch_bounds__(256) void k_zgemm(
    const double* __restrict__ Ab, const double* __restrict__ Bb,
    double* __restrict__ Cb, const double* __restrict__ Db,
    int preA, int preB, double alpha, double beta, double gamma,
    double* __restrict__ ws, int fm, int round,
    long sA, long sB, long sC)
{
    int z = blockIdx.z;
    const double* A = Ab + (size_t)z * sA;
    const double* B = Bb + (size_t)z * sB;
    double* C = Cb + (size_t)z * sC;
    int tx = threadIdx.x & 15, ty = threadIdx.x >> 4;
    int row = blockIdx.y * 16 + ty, col = blockIdx.x * 16 + tx;
    if (fm == 1 && round > (int)ws[SC_EXPM_S]){
        C[row*256 + col] = A[row*256 + col];
        C[NN + row*256 + col] = A[NN + row*256 + col];
        return;
    }
    __shared__ double Asr[16][17], Asi[16][17], Bsr[16][17], Bsi[16][17];
    double cr = 0.0, ci = 0.0;
    for (int k0 = 0; k0 < 256; k0 += 16){
        int ac = k0 + tx;
        double a_re = A[row*256 + ac], a_im = A[NN + row*256 + ac];
        if (preA == 1) a_im = -a_im;
        else if (preA == 2){ if (row == ac) a_re -= 1.0; }
        int br = k0 + ty;
        double b_re = B[br*256 + col], b_im = B[NN + br*256 + col];
        if (preB == 1){ b_re = ((br == col) ? 2.0 : 0.0) - b_re; b_im = -b_im; }
        Asr[ty][tx] = a_re; Asi[ty][tx] = a_im;
        Bsr[ty][tx] = b_re; Bsi[ty][tx] = b_im;
        __syncthreads();
        #pragma unroll
        for (int kk = 0; kk < 16; kk++){
            double xr = Asr[ty][kk], xi = Asi[ty][kk];
            double yr = Bsr[kk][tx], yi = Bsi[kk][tx];
            cr += xr*yr - xi*yi;
            ci += xr*yi + xi*yr;
        }
        __syncthreads();
    }
    double outr = alpha * cr, outi = alpha * ci;
    if (Db){ outr += beta * Db[row*256 + col]; outi += beta * Db[NN + row*256 + col]; }
    if (row == col) outr += gamma;
    C[row*256 + col] = outr;
    C[NN + row*256 + col] = outi;
}

// ---- elementwise: C = a1*f1*X1 + a2*X2 + a3*X3 + a4*X4 + g*I ; mode1: f1=expm scale
__global__ __launch_bounds__(256) void k_combine(double* ws, int dst,
    int s1, int s2, int s3, int s4,
    double a1, double a2, double a3, double a4, double g, int mode)
{
    int ij = blockIdx.x * 256 + threadIdx.x;
    int i = ij >> 8, j = ij & 255;
    double f1 = (mode == 1) ? ws[SC_EXPM_SCALE] : 1.0;
    double* C = ws + MAT0 + (size_t)dst * MATD;
    double r = 0.0, m = 0.0;
    if (s1 >= 0){ const double* X = ws + MAT0 + (size_t)s1 * MATD; r += a1*f1*X[ij]; m += a1*f1*X[NN+ij]; }
    if (s2 >= 0){ const double* X = ws + MAT0 + (size_t)s2 * MATD; r += a2*X[ij]; m += a2*X[NN+ij]; }
    if (s3 >= 0){ const double* X = ws + MAT0 + (size_t)s3 * MATD; r += a3*X[ij]; m += a3*X[NN+ij]; }
    if (s4 >= 0){ const double* X = ws + MAT0 + (size_t)s4 * MATD; r += a4*X[ij]; m += a4*X[NN+ij]; }
    if (i == j) r += g;
    C[ij] = r; C[NN + ij] = m;
}

__global__ void k_expm_prep(double* ws)
{
    if (threadIdx.x == 0 && blockIdx.x == 0){
        double n1 = ws[8];
        int s = 0;
        if (n1 > 0.5){
            s = (int)ceil(log2(n1 / 0.5));
            if (s < 0) s = 0; if (s > 10) s = 10;
        }
        ws[SC_EXPM_S] = (double)s;
        ws[SC_EXPM_SCALE] = ldexp(1.0, -s);
    }
}

// ================= cooperative logm chain (v2: 1024 thr, 4-way k-split) =========
// grid 256 blocks x 1024 threads. Thread t: quarter q=t>>8, tq=t&255, tile coords
// (ty,tx) from tq; block b -> output tile (b>>4, b&15). Quarter q accumulates
// k in [64q,64q+64); partials reduced in LDS; (cr,ci) identical on all quarters.
__global__ __launch_bounds__(1024, 4) void k_chain(double* ws)
{
    cg::grid_group grid = cg::this_grid();
    const int t  = threadIdx.x;
    const int q  = t >> 8;
    const int tq = t & 255;
    const int tx = tq & 15, ty = tq >> 4;
    const int b  = blockIdx.x;
    const int bx = b & 15, by = b >> 4;
    const int row = by*16 + ty, col = bx*16 + tx;
    const int ij = row*256 + col;

    __shared__ double Asr[4][16][17], Asi[4][16][17];
    __shared__ double Bsr[4][16][17], Bsi[4][16][17];
    __shared__ double red[1024];

    auto MPd = [&](int s)->double*{ return ws + MAT0 + (size_t)s * MATD; };

    auto bsum = [&](double v)->double {
        red[t] = v; __syncthreads();
        for (int s = 512; s > 0; s >>= 1){ if (t < s) red[t] += red[t+s]; __syncthreads(); }
        double r = red[0]; __syncthreads();
        return r;
    };
    auto gmax = [&](int base)->double {   // identical in all blocks
        red[t] = (t < 256) ? ws[base + t] : 0.0; __syncthreads();
        for (int s = 512; s > 0; s >>= 1){ if (t < s) red[t] = fmax(red[t], red[t+s]); __syncthreads(); }
        double r = red[0]; __syncthreads();
        return r;
    };

    // C_partial: quarter q covers k in [64q, 64q+64) as 4 LDS substeps of 16.
    // Returns fully reduced (cr,ci), valid on ALL threads (same value per (ty,tx)).
    auto zmm = [&](const double* A, const double* B, int preA, int preB,
                   double& cr, double& ci){
        double pr = 0.0, pi = 0.0;
        #pragma unroll
        for (int s2 = 0; s2 < 4; s2++){
            int k0 = (q << 6) + (s2 << 4);
            int ac = k0 + tx;
            double a_re = A[row*256 + ac], a_im = A[NN + row*256 + ac];
            if (preA == 2 && row == ac) a_re -= 1.0;
            int br = k0 + ty;
            double b_re = B[br*256 + col], b_im = B[NN + br*256 + col];
            if (preB == 1){ b_re = ((br == col) ? 2.0 : 0.0) - b_re; b_im = -b_im; }
            Asr[q][ty][tx] = a_re; Asi[q][ty][tx] = a_im;
            Bsr[q][ty][tx] = b_re; Bsi[q][ty][tx] = b_im;
            __syncthreads();
            #pragma unroll
            for (int kk = 0; kk < 16; kk++){
                double xr = Asr[q][ty][kk], xi = Asi[q][ty][kk];
                double yr = Bsr[q][kk][tx], yi = Bsi[q][kk][tx];
                pr += xr*yr - xi*yi;
                pi += xr*yi + xi*yr;
            }
            __syncthreads();
        }
        red[t] = pr; __syncthreads();
        cr = red[tq] + red[tq+256] + red[tq+512] + red[tq+768];
        __syncthreads();
        red[t] = pi; __syncthreads();
        ci = red[tq] + red[tq+256] + red[tq+512] + red[tq+768];
        __syncthreads();
    };

    // col/row sums of |M| (col b, row b), colsum of |M-I|; zero NS residual bufs
    auto norm_phase = [&](const double* M){
        double c = 0.0, cm = 0.0, rr = 0.0;
        if (t < 256){
            double mr = M[t*256 + b], mi = M[NN + t*256 + b];
            c  = fabs(mr) + fabs(mi);
            cm = fabs(mr - ((t == b) ? 1.0 : 0.0)) + fabs(mi);
            rr = fabs(M[b*256 + t]) + fabs(M[NN + b*256 + t]);
        }
        double sc = bsum(c), scm = bsum(cm), sr = bsum(rr);
        if (t == 0){
            ws[CS_M + b] = sc; ws[CS_MI + b] = scm; ws[RS_M + b] = sr;
            ws[RS_A + b] = 0.0; ws[RS_B + b] = 0.0;
        }
    };
    auto normI_phase = [&](const double* M){
        double c = 0.0, rr = 0.0;
        if (t < 256){
            c  = fabs(M[t*256 + b]) + fabs(M[NN + t*256 + b]);
            rr = fabs(M[b*256 + t]) + fabs(M[NN + b*256 + t]);
        }
        double sc = bsum(c), sr = bsum(rr);
        if (t == 0){ ws[CS_I + b] = sc; ws[RS_I + b] = sr; }
    };
    auto cold_phase = [&](const double* M, double* X, double nu){
        if (q == 0){
            X[ij]      =  M[col*256 + row] * nu;
            X[NN + ij] = -M[NN + col*256 + row] * nu;
        }
        if (t == 0){ ws[RS_A + b] = 0.0; ws[RS_B + b] = 0.0; }
    };
    // T = M*X, accumulate colsums of |T - I| into ws[cur..], zero ws[oth..]
    auto t_phase = [&](const double* M, const double* X, double* T, int cur, int oth){
        double cr, ci; zmm(M, X, 0, 0, cr, ci);
        if (q == 0){
            T[ij] = cr; T[NN + ij] = ci;
            red[tq] = fabs(cr - ((row == col) ? 1.0 : 0.0)) + fabs(ci);
        } else red[t] = 0.0;
        __syncthreads();
        if (t < 16){
            double s = 0.0;
            #pragma unroll
            for (int h = 0; h < 16; h++) s += red[h*16 + t];
            atomicAdd(&ws[cur + (bx*16 + t)], s);
        }
        if (t == 0) ws[oth + b] = 0.0;
        __syncthreads();
    };
    auto x_phase = [&](const double* X, const double* T, double* Xo){
        double cr, ci; zmm(X, T, 0, 1, cr, ci);
        if (q == 0){ Xo[ij] = cr; Xo[NN + ij] = ci; }
    };

    int invslot = S_X;
    bool haveWarm = false;

    // NS inverse of slot mslot -> invslot. Warm start from previous inverse with
    // rigorous fallback (n1 residual >= 0.9 -> cold restart X0 = M^H/(n1*ninf)).
    auto inv_dev = [&](int mslot, int cap, double nmprod){
        bool warm = haveWarm;
        int xc = warm ? invslot : S_X;
        int xo = (xc == S_X) ? S_X2 : S_X;
        if (!warm){
            cold_phase(MPd(mslot), MPd(xc), 1.0 / nmprod);
            grid.sync();
        }
        for (int k = 0; k < cap; k++){
            int cur = (k & 1) ? RS_B : RS_A;
            int oth = (k & 1) ? RS_A : RS_B;
            t_phase(MPd(mslot), MPd(xc), MPd(S_T), cur, oth);
            grid.sync();
            double r = gmax(cur);          // n1(I - M X), uniform
            if (k == 0 && warm && r >= 0.9){
                grid.sync();               // all readers done before cold writes
                cold_phase(MPd(mslot), MPd(xc), 1.0 / nmprod);
                grid.sync();
                warm = false; k = -1; continue;
            }
            if (r < 2e-10) break;
            x_phase(MPd(xc), MPd(S_T), MPd(xo));
            grid.sync();
            int tmp = xc; xc = xo; xo = tmp;
        }
        invslot = xc;
        haveWarm = true;
    };

    const int DBCAP[6] = {22, 12, 10, 10, 8, 8};
    const int NSCAP[6] = {44, 24, 20, 18, 16, 16};
    int yc = S_Y, yo = S_Y2;

    for (int st = 0; st < 6; st++){
        if (q == 0){   // stage init: M = A (and stage 0: Y = A)
            const double* A = MPd(st == 0 ? S_EW : yc);
            double* Md = MPd(S_M);
            double vr = A[ij], vi = A[NN + ij];
            Md[ij] = vr; Md[NN + ij] = vi;
            if (st == 0){ double* Yd = MPd(S_Y); Yd[ij] = vr; Yd[NN + ij] = vi; }
        }
        grid.sync();
        int mc = S_M, mo = S_M2;
        for (int it = 0; it < DBCAP[st]; it++){
            norm_phase(MPd(mc));
            grid.sync();
            double n1m = gmax(CS_M), nfm = gmax(RS_M), nmi = gmax(CS_MI);
            if (nmi < 2e-9) break;                  // M -> I: stage converged
            inv_dev(mc, NSCAP[st], n1m * nfm);
            normI_phase(MPd(invslot));
            grid.sync();
            double n1i = gmax(CS_I), nfi = gmax(RS_I);
            double mu = pow((n1i * nfi) / (n1m * nfm), 0.125);
            mu = fmin(fmax(mu, 0.125), 8.0);
            {   // fused: Y' = 0.5(mu Y + mu^-1 Y M^-1);  M' = 0.5I + 0.25(mu^2 M + mu^-2 M^-1)
                const double* Y = MPd(yc); const double* IY = MPd(invslot); const double* M = MPd(mc);
                double* Yo = MPd(yo); double* Mo = MPd(mo);
                double cr, ci; zmm(Y, IY, 0, 0, cr, ci);
                if (q == 0){
                    double hmu = 0.5*mu, hmi = 0.5/mu;
                    Yo[ij]      = hmu*Y[ij]      + hmi*cr;
                    Yo[NN + ij] = hmu*Y[NN + ij] + hmi*ci;
                    double q2 = 0.25*mu*mu, qi2 = 0.25/(mu*mu);
                    Mo[ij]      = q2*M[ij]      + qi2*IY[ij] + ((row == col) ? 0.5 : 0.0);
                    Mo[NN + ij] = q2*M[NN + ij] + qi2*IY[NN + ij];
                }
            }
            grid.sync();
            int tp = mc; mc = mo; mo = tp;
            tp = yc; yc = yo; yo = tp;
        }
    }

    // Cayley: W = (B - I)(B + I)^-1 , B = Ew^(1/64) in slot yc
    if (q == 0){
        const double* Bm = MPd(yc); double* C = MPd(S_M);
        C[ij] = Bm[ij] + ((row == col) ? 1.0 : 0.0);
        C[NN + ij] = Bm[NN + ij];
    }
    grid.sync();
    norm_phase(MPd(S_M));
    grid.sync();
    {
        double n1c = gmax(CS_M), nfc = gmax(RS_M);
        inv_dev(S_M, 24, n1c * nfc);
    }
    { double cr, ci; zmm(MPd(yc), MPd(invslot), 2, 0, cr, ci);
      if (q == 0){ double* W = MPd(S_W); W[ij] = cr; W[NN + ij] = ci; } }
    grid.sync();
    { double cr, ci; zmm(MPd(S_W), MPd(S_W), 0, 0, cr, ci);
      if (q == 0){ double* V = MPd(S_V); V[ij] = cr; V[NN + ij] = ci; } }
    grid.sync();
    if (q == 0){ double* P = MPd(S_G);
      P[ij] = (row == col) ? (1.0/39.0) : 0.0; P[NN + ij] = 0.0; }
    grid.sync();
    int gc = S_G, go = S_G2;
    for (int j = 18; j >= 0; j--){   // artanh(W) = W * sum_{j=0}^{19} V^j/(2j+1), deg 39
        double cr, ci; zmm(MPd(S_V), MPd(gc), 0, 0, cr, ci);
        if (q == 0){
            double* G = MPd(go);
            G[ij] = cr + ((row == col) ? 1.0/(double)(2*j + 1) : 0.0);
            G[NN + ij] = ci;
        }
        grid.sync();
        int tmp = gc; gc = go; go = tmp;
    }
    { double cr, ci; zmm(MPd(S_W), MPd(gc), 0, 0, cr, ci);
      if (q == 0){ double* L = MPd(S_LAT); L[ij] = cr; L[NN + ij] = ci; } }
    grid.sync();
    if (q == 0){   // S = 128 * conj(LAT - LAT^T)
        const double* L = MPd(S_LAT); double* S = MPd(PBASE);
        S[ij]      =  128.0 * (L[ij] - L[col*256 + row]);
        S[NN + ij] = -128.0 * (L[NN + ij] - L[NN + col*256 + row]);
    }
}

// theta per u (rigorous upper bound); theta>4 -> scaling+squaring pool
__global__ __launch_bounds__(256) void k_theta_pool(double* ws)
{
    __shared__ double th[256]; __shared__ int rk[256];
    int t = threadIdx.x;
    double nS = ws[SC_NORMS2];
    double cr = ws[W_C_RE + t], ci = ws[W_C_IM + t];
    th[t] = sqrt(cr*cr + ci*ci) * nS;
    __syncthreads();
    int r = 0;
    for (int v = 0; v < 256; v++){
        if (th[v] > th[t] || (th[v] == th[t] && v < t)) r++;
    }
    rk[t] = r;
    __syncthreads();
    if (t == 0){
        int cnt = 0;
        for (int u = 0; u < 256; u++){
            double s = 0.0; int slot = -1;
            if (th[u] > 4.0 && rk[u] < NPOOL){
                double e = ceil(log2(th[u] / 4.0));
                if (e < 1.0) e = 1.0; if (e > 12.0) e = 12.0;
                s = e; slot = cnt;
                ws[W_SLOTU + cnt] = (double)u;
                cnt++;
            }
            ws[W_SU + u] = s;
            ws[W_SLOT + u] = (double)slot;
        }
        for (int k = cnt; k < NPOOL; k++) ws[W_SLOTU + k] = -1.0;
    }
}

// weights w[u][k] = (c_u / 2^{s_u})^k / k!
__global__ __launch_bounds__(256) void k_weights(double* ws)
{
    int u = threadIdx.x;
    double sc = ldexp(1.0, -(int)ws[W_SU + u]);
    double cr = ws[W_C_RE + u] * sc, ci = ws[W_C_IM + u] * sc;
    double wr = 1.0, wi = 0.0;
    ws[W_W + (u*33)*2] = 1.0; ws[W_W + (u*33)*2 + 1] = 0.0;
    for (int k = 1; k <= 32; k++){
        double inv = 1.0 / (double)k;
        double nr = (wr*cr - wi*ci) * inv, ni = (wr*ci + wi*cr) * inv;
        wr = nr; wi = ni;
        ws[W_W + (u*33 + k)*2] = wr;
        ws[W_W + (u*33 + k)*2 + 1] = wi;
    }
}

// exp_tens[u] = sum_k w[u][k] S^k -> f32 out (non-pooled, pass 0) or fp64 pool base
__global__ __launch_bounds__(256) void k_combo(double* ws, float* out, long off_ex, int f,
                                               int pass, int K)
{
    __shared__ double wre[16][33], wim[16][33];
    __shared__ int anywork;
    int t = threadIdx.x;
    int row = blockIdx.x, ug = blockIdx.y;
    if (t == 0) anywork = (pass == 0) ? 1 : 0;
    __syncthreads();
    if (pass > 0 && t < 16){
        int u = ug*16 + t;
        int slot = (int)ws[W_SLOT + u];
        int phys = slot - pass * K;
        if (slot >= 0 && phys >= 0 && phys < K) anywork = 1;
    }
    __syncthreads();
    if (!anywork) return;
    for (int i = t; i < 16*33; i += 256){
        int g = i / 33, k = i % 33;
        int u = ug*16 + g;
        wre[g][k] = ws[W_W + (u*33 + k)*2];
        wim[g][k] = ws[W_W + (u*33 + k)*2 + 1];
    }
    __syncthreads();
    int j = t, ij = row*256 + j;
    double ar[16], ai[16];
    #pragma unroll
    for (int g = 0; g < 16; g++){
        ar[g] = (row == j) ? wre[g][0] : 0.0;
        ai[g] = (row == j) ? wim[g][0] : 0.0;
    }
    for (int k = 1; k <= 32; k++){
        const double* SP = ws + MAT0 + (size_t)(PBASE + k - 1) * MATD;
        double sre = SP[ij], sim = SP[NN + ij];
        #pragma unroll
        for (int g = 0; g < 16; g++){
            ar[g] += wre[g][k]*sre - wim[g][k]*sim;
            ai[g] += wre[g][k]*sim + wim[g][k]*sre;
        }
    }
    for (int g = 0; g < 16; g++){
        int u = ug*16 + g;
        int slot = (int)ws[W_SLOT + u];
        if (slot >= 0){
            int phys = slot - pass * K;
            if (phys >= 0 && phys < K){
                double* P = ws + MAT0 + (size_t)(POOL0 + phys) * MATD;
                P[ij] = ar[g]; P[NN + ij] = ai[g];
            }
        } else if (pass == 0){
            long base = off_ex + (long)u * NN * f + (long)ij * f;
            out[base] = (float)ar[g];
            if (f == 2) out[base + 1] = (float)ai[g];
        }
    }
}

// pool squaring: virtual slot = pass*K + z; square only if round <= s_u
__global__ __launch_bounds__(256) void k_pool_sq(double* ws, int round, int pass, int K)
{
    int z = blockIdx.z;
    int vs = pass * K + z;
    int u = (vs < NPOOL) ? (int)ws[W_SLOTU + vs] : -1;
    if (u < 0) return;
    if (round > (int)ws[W_SU + u]) return;
    const double* A = ws + MAT0 + (size_t)(POOL0 + ((round & 1) ? 0 : K) + z) * MATD;
    double* C = ws + MAT0 + (size_t)(POOL0 + ((round & 1) ? K : 0) + z) * MATD;
    int tx = threadIdx.x & 15, ty = threadIdx.x >> 4;
    int row = blockIdx.y*16 + ty, col = blockIdx.x*16 + tx;
    __shared__ double Asr[16][17], Asi[16][17], Bsr[16][17], Bsi[16][17];
    double cr = 0.0, ci = 0.0;
    for (int k0 = 0; k0 < 256; k0 += 16){
        Asr[ty][tx] = A[row*256 + k0 + tx];
        Asi[ty][tx] = A[NN + row*256 + k0 + tx];
        Bsr[ty][tx] = A[(k0 + ty)*256 + col];
        Bsi[ty][tx] = A[NN + (k0 + ty)*256 + col];
        __syncthreads();
        #pragma unroll
        for (int kk = 0; kk < 16; kk++){
            double xr = Asr[ty][kk], xi = Asi[ty][kk];
            double yr = Bsr[kk][tx], yi = Bsi[kk][tx];
            cr += xr*yr - xi*yi;
            ci += xr*yi + xi*yr;
        }
        __syncthreads();
    }
    C[row*256 + col] = cr;
    C[NN + row*256 + col] = ci;
}

__global__ __launch_bounds__(256) void k_pool_out(const double* ws, float* out, long off_ex,
                                                  int f, int pass, int K)
{
    int z = blockIdx.y;
    int vs = pass * K + z;
    int u = (vs < NPOOL) ? (int)ws[W_SLOTU + vs] : -1;
    if (u < 0) return;
    int su = (int)ws[W_SU + u];
    int ij = blockIdx.x * 256 + threadIdx.x;
    const double* P = ws + MAT0 + (size_t)(POOL0 + ((su & 1) ? K : 0) + z) * MATD;
    long base = off_ex + (long)u * NN * f + (long)ij * f;
    out[base] = (float)P[ij];
    if (f == 2) out[base + 1] = (float)P[NN + ij];
}

__global__ __launch_bounds__(256) void k_cast_out(const double* ws, int slot, float* out, long off, int f)
{
    int ij = blockIdx.x * 256 + threadIdx.x;
    const double* P = ws + MAT0 + (size_t)slot * MATD;
    out[off + (long)ij * f] = (float)P[ij];
    if (f == 2) out[off + (long)ij * f + 1] = (float)P[NN + ij];
}

// ============================ host ============================
extern "C" void kernel_launch(void* const* d_in, const int* in_sizes, int n_in,
                              void* d_out, int out_size, void* d_ws, size_t ws_size,
                              hipStream_t stream)
{
    double* ws = (double*)d_ws;
    float* out = (float*)d_out;

    int f = (out_size >= 33816832) ? 2 : 1;
    long off_ex = 256;
    long off_uw = off_ex + (long)f * 16777216L;
    long off_ew = off_uw + (long)f * 65536L;

    k_init<<<128, 256, 0, stream>>>(ws);
    k_detect<<<1, 64, 0, stream>>>(d_in[0], ws);
    k_small<<<1, 256, 0, stream>>>(d_in[0], d_in[1], d_in[2], d_in[3], d_in[4], ws, out);

    long slotsAvail = (long)(ws_size / 8 - MAT0) / MATD;
    if (slotsAvail < POOL0 + 32) return;   // need >= 52 work slots + 16x2 pool (~88.3 MB)
    int K = (int)((slotsAvail - POOL0) / 2);
    if (K > NPOOL) K = NPOOL;
    if (K < 16) K = 16;
    int P = (NPOOL + K - 1) / K;

    auto MP = [&](int s){ return ws + MAT0 + (size_t)s * MATD; };
    auto ZG = [&](int a, int b, int c, int preA, int preB, double al, double be,
                  int d, double ga, int fm, int round){
        k_zgemm<<<dim3(16,16,1), 256, 0, stream>>>(MP(a), MP(b), MP(c),
            d >= 0 ? MP(d) : nullptr, preA, preB, al, be, ga, ws,
            fm, round, 0L, 0L, 0L);
    };
    auto GEMM = [&](int a, int b, int c, int preA, int preB, double al, double be, int d, double ga){
        ZG(a, b, c, preA, preB, al, be, d, ga, 0, 0);
    };

    k_build_mats<<<256, 256, 0, stream>>>(d_in[5], d_in[6], d_in[7], d_in[8], ws);
    k_cast_out<<<256, 256, 0, stream>>>(ws, S_NUW, out, off_uw, f);

    // -------- expm(new_uw): scaling + Paterson-Stockmeyer deg-16 Taylor + squarings ----
    static const double INVF[17] = {
        1.0, 1.0, 0.5, 1.0/6.0, 1.0/24.0, 1.0/120.0, 1.0/720.0, 1.0/5040.0,
        1.0/40320.0, 1.0/362880.0, 1.0/3628800.0, 1.0/39916800.0, 1.0/479001600.0,
        1.0/6227020800.0, 1.0/87178291200.0, 1.0/1307674368000.0, 1.0/20922789888000.0 };
    k_norm1inf<<<1, 256, 0, stream>>>(MP(S_NUW), ws, 8);
    k_expm_prep<<<1, 64, 0, stream>>>(ws);
    k_combine<<<256, 256, 0, stream>>>(ws, S_LAT, S_NUW, -1, -1, -1, 1.0, 0, 0, 0, 0.0, 1); // T = 2^-s NUW
    GEMM(S_LAT, S_LAT, S_T2, 0, 0, 1.0, 0.0, -1, 0.0);
    GEMM(S_T2, S_LAT, S_T3, 0, 0, 1.0, 0.0, -1, 0.0);
    GEMM(S_T2, S_T2, S_T4, 0, 0, 1.0, 0.0, -1, 0.0);
    k_combine<<<256, 256, 0, stream>>>(ws, S_E1, -1, -1, -1, -1, 0, 0, 0, 0, INVF[16], 0);
    for (int b = 3; b >= 0; b--){
        GEMM(S_T4, S_E1, S_E2, 0, 0, 1.0, 0.0, -1, 0.0);
        k_combine<<<256, 256, 0, stream>>>(ws, S_E1, S_E2, S_LAT, S_T2, S_T3,
            1.0, INVF[4*b+1], INVF[4*b+2], INVF[4*b+3], INVF[4*b], 0);
    }
    for (int r = 1; r <= 10; r++){
        int src = (r & 1) ? S_E1 : S_E2, dst = (r & 1) ? S_E2 : S_E1;
        ZG(src, src, dst, 0, 0, 1.0, 0.0, -1, 0.0, 1, r);
    }
    GEMM(S_EW, S_E1, S_M2, 1, 0, 1.0, 0.0, -1, 0.0);   // new_Ew = conj(Ew) expm(new_uw)
    k_cast_out<<<256, 256, 0, stream>>>(ws, S_M2, out, off_ew, f);

    // -------- logm(Ew): single cooperative kernel (v2: 1024 thr, 4-way k-split) ----
    {
        void* chainArgs[] = { (void*)&ws };
        hipLaunchCooperativeKernel((const void*)k_chain, dim3(256), dim3(1024),
                                   chainArgs, 0, stream);
    }

    // -------- batched exp_tens = expm(c_u S): shared powers + pooled squaring --------
    k_norm1inf<<<1, 256, 0, stream>>>(MP(PBASE), ws, 12);   // rigorous norm bound inputs
    k_fro<<<1, 256, 0, stream>>>(MP(PBASE), ws);
    k_snorm<<<1, 1, 0, stream>>>(ws);
    k_theta_pool<<<1, 256, 0, stream>>>(ws);
    k_weights<<<1, 256, 0, stream>>>(ws);
    for (int m = 1; m < 32; m *= 2){
        int cnt = (m < 32 - m) ? m : (32 - m);
        k_zgemm<<<dim3(16,16,cnt), 256, 0, stream>>>(MP(PBASE + m - 1), MP(PBASE), MP(PBASE + m),
            nullptr, 0, 0, 1.0, 0.0, 0.0, ws, 0, 0, 0L, MATD, MATD);
    }
    for (int p = 0; p < P; p++){
        k_combo<<<dim3(256,16), 256, 0, stream>>>(ws, out, off_ex, f, p, K);
        for (int r = 1; r <= 12; r++)
            k_pool_sq<<<dim3(16,16,K), 256, 0, stream>>>(ws, r, p, K);
        k_pool_out<<<dim3(256,K), 256, 0, stream>>>(ws, out, off_ex, f, p, K);
    }
}